// Round 2
// baseline (4138.871 us; speedup 1.0000x reference)
//
#include <hip/hip_runtime.h>
#include <cstdint>
#include <cstddef>

#define BB   4
#define CIN  64
#define VV   50000
#define COUT 128
#define KK   7
#define NV   32

// ---------------------------------------------------------------------------
// Kernel T: transpose x[B][C][V] -> xt[B][V][C] so the per-vertex gather of a
// full channel column becomes one contiguous 256B read.
// ---------------------------------------------------------------------------
__global__ __launch_bounds__(256) void transpose_k(const float* __restrict__ x,
                                                   float* __restrict__ xt) {
    __shared__ float tile[64][65];  // +1 pad: conflict-free transposed reads
    int b    = blockIdx.y;
    int v0   = blockIdx.x * 64;
    int lane = threadIdx.x & 63;
    int row  = threadIdx.x >> 6;  // 0..3
#pragma unroll
    for (int i = 0; i < 16; i++) {
        int c = row + 4 * i;
        int v = v0 + lane;
        float val = 0.f;
        if (v < VV) val = x[((size_t)b * CIN + c) * VV + v];
        tile[c][lane] = val;
    }
    __syncthreads();
#pragma unroll
    for (int i = 0; i < 16; i++) {
        int v = v0 + row + 4 * i;
        if (v < VV) xt[((size_t)b * VV + v) * CIN + lane] = tile[lane][row + 4 * i];
    }
}

// ---------------------------------------------------------------------------
// Kernel P: pack W[o][c][7] -> Wp[c][o][8]  (c-major! k padded with 0).
// At GEMM step c the wave then reads a contiguous 4KB slab -> coalesced.
// ---------------------------------------------------------------------------
__global__ __launch_bounds__(256) void pack_w_k(const float* __restrict__ W,
                                                float* __restrict__ Wp) {
    int i = blockIdx.x * 256 + threadIdx.x;  // over COUT*CIN = 8192 rows
    if (i < COUT * CIN) {
        int o = i / CIN;
        int c = i % CIN;
        const float* src = W + (size_t)i * 7;
        float4 a, b;
        a.x = src[0]; a.y = src[1]; a.z = src[2]; a.w = src[3];
        b.x = src[4]; b.y = src[5]; b.z = src[6]; b.w = 0.f;
        float4* dst = (float4*)(Wp + ((size_t)c * COUT + o) * 8);
        dst[0] = a;
        dst[1] = b;
    }
}

// ---------------------------------------------------------------------------
// Kernel M: per block: batch b, 32-vertex tile.
//  Phase 1: gather f0..f3 (coalesced via xt), compute 7 symmetric features
//           per (v,c) into LDS G[32][512] (k padded to 8).  64 KB.
//  Phase 2: thread = 4 outputs x 4 vertices (og=t&31, vg=t>>5).
//           W from global (c-major, coalesced, L1/L2-resident);
//           G via broadcast ds_read_b128. 112 FMA : 8 LDS : 8 VMEM per c.
// ---------------------------------------------------------------------------
__global__ __launch_bounds__(256) void mesh_k(
        const float* __restrict__ x, const float* __restrict__ xt,
        const void* __restrict__ Gi, const float* __restrict__ Wp,
        const float* __restrict__ Wraw, const float* __restrict__ bias,
        float* __restrict__ out, int use_xt, int use_wp) {
    __shared__ float Gl[NV][CIN * 8];  // 64 KB

    int b   = blockIdx.y;
    int v0  = blockIdx.x * NV;
    int t   = threadIdx.x;
    int lc  = t & 63;   // channel lane
    int grp = t >> 6;   // 0..3

    // Gi dtype sniff: int64 (little-endian, in-range values => high dwords 0)
    // vs int32. Wave-uniform branch.
    const unsigned* gu = (const unsigned*)Gi;
    bool is64 = ((gu[1] | gu[3] | gu[5] | gu[7]) == 0u);

    // ---- Phase 1: build G in LDS ----
#pragma unroll
    for (int p = 0; p < NV / 4; ++p) {
        int vv = p * 4 + grp;
        int v  = v0 + vv;
        if (v < VV) {
            long long i0, i1, i2, i3;
            size_t gbase = ((size_t)b * VV + v) * 4;
            if (is64) {
                const long long* g8 = (const long long*)Gi + gbase;
                i0 = g8[0]; i1 = g8[1]; i2 = g8[2]; i3 = g8[3];
            } else {
                const int* g4 = (const int*)Gi + gbase;
                i0 = g4[0]; i1 = g4[1]; i2 = g4[2]; i3 = g4[3];
            }
            i0 = i0 < 0 ? 0 : (i0 >= VV ? VV - 1 : i0);
            i1 = i1 < 0 ? 0 : (i1 >= VV ? VV - 1 : i1);
            i2 = i2 < 0 ? 0 : (i2 >= VV ? VV - 1 : i2);
            i3 = i3 < 0 ? 0 : (i3 >= VV ? VV - 1 : i3);

            float f0, f1, f2, f3;
            if (use_xt) {
                const float* base = xt + (size_t)b * VV * CIN + lc;
                f0 = base[(size_t)i0 * CIN];
                f1 = base[(size_t)i1 * CIN];
                f2 = base[(size_t)i2 * CIN];
                f3 = base[(size_t)i3 * CIN];
            } else {
                const float* base = x + ((size_t)b * CIN + lc) * VV;
                f0 = base[i0]; f1 = base[i1]; f2 = base[i2]; f3 = base[i3];
            }

            float s1  = f1 + f2 + f3;
            float p12 = f1 * f2, p13 = f1 * f3, p23 = f2 * f3;
            float g2  = p12 * f3;
            float g3  = p12 + p13 + p23;
            float g4  = f1 * f1 + f2 * f2 + f3 * f3;
            float g5  = fabsf(f1 - f2) + fabsf(f1 - f3) + fabsf(f2 - f3);
            float g6  = f1 * f1 * f1 + f2 * f2 * f2 + f3 * f3 * f3;

            float* gl = &Gl[vv][lc * 8];
            gl[0] = f0; gl[1] = s1; gl[2] = g2; gl[3] = g3;
            gl[4] = g4; gl[5] = g5; gl[6] = g6; gl[7] = 0.f;
        }
    }
    __syncthreads();

    // ---- Phase 2: out[4 o-rows, 4 v] per thread ----
    int og = t & 31;          // o-group: outputs og*4 .. og*4+3
    int vg = t >> 5;          // v-group: vertices vg*4 .. vg*4+3
    int o0 = og * 4;
    int vb = vg * 4;

    float acc[4][4];
#pragma unroll
    for (int r = 0; r < 4; r++) {
        float bv = bias[o0 + r];
#pragma unroll
        for (int j = 0; j < 4; j++) acc[r][j] = bv;
    }

    for (int c = 0; c < CIN; ++c) {
        float4 wa[4], wb[4];
        if (use_wp) {
            const float4* wp = (const float4*)(Wp + ((size_t)c * COUT + o0) * 8);
#pragma unroll
            for (int r = 0; r < 4; r++) { wa[r] = wp[2 * r]; wb[r] = wp[2 * r + 1]; }
        } else {
#pragma unroll
            for (int r = 0; r < 4; r++) {
                const float* p = Wraw + ((size_t)(o0 + r) * CIN + c) * 7;
                wa[r] = make_float4(p[0], p[1], p[2], p[3]);
                wb[r] = make_float4(p[4], p[5], p[6], 0.f);
            }
        }
        float4 ga[4], gb[4];
#pragma unroll
        for (int j = 0; j < 4; j++) {
            const float4* g4p = (const float4*)&Gl[vb + j][c * 8];
            ga[j] = g4p[0];
            gb[j] = g4p[1];
        }
#pragma unroll
        for (int r = 0; r < 4; r++) {
#pragma unroll
            for (int j = 0; j < 4; j++) {
                acc[r][j] += wa[r].x * ga[j].x + wa[r].y * ga[j].y
                           + wa[r].z * ga[j].z + wa[r].w * ga[j].w
                           + wb[r].x * gb[j].x + wb[r].y * gb[j].y
                           + wb[r].z * gb[j].z;
            }
        }
    }

    // ---- Store: 4 rows x float4 ----
    int v = v0 + vb;
#pragma unroll
    for (int r = 0; r < 4; r++) {
        float* po = out + ((size_t)b * COUT + o0 + r) * VV + v;
        if (v + 3 < VV) {
            *(float4*)po = make_float4(acc[r][0], acc[r][1], acc[r][2], acc[r][3]);
        } else {
            for (int i = 0; i < 4; i++)
                if (v + i < VV) po[i] = acc[r][i];
        }
    }
}

// ---------------------------------------------------------------------------
extern "C" void kernel_launch(void* const* d_in, const int* in_sizes, int n_in,
                              void* d_out, int out_size, void* d_ws, size_t ws_size,
                              hipStream_t stream) {
    const float* x    = (const float*)d_in[0];
    const void*  Gi   = d_in[1];
    const float* W    = (const float*)d_in[2];
    const float* bias = (const float*)d_in[3];
    float* out        = (float*)d_out;

    size_t xt_bytes = (size_t)BB * VV * CIN * sizeof(float);   // 51.2 MB
    size_t wp_bytes = (size_t)COUT * CIN * 8 * sizeof(float);  // 256 KB

    int use_xt = 0, use_wp = 0;
    float* xt = nullptr;
    float* Wp = nullptr;
    if (ws_size >= xt_bytes + wp_bytes) {
        xt = (float*)d_ws;
        Wp = (float*)((char*)d_ws + xt_bytes);
        use_xt = 1; use_wp = 1;
    } else if (ws_size >= wp_bytes) {
        Wp = (float*)d_ws;
        use_wp = 1;
    }

    if (use_xt) {
        dim3 g((VV + 63) / 64, BB);
        transpose_k<<<g, 256, 0, stream>>>(x, xt);
    }
    if (use_wp) {
        pack_w_k<<<(COUT * CIN + 255) / 256, 256, 0, stream>>>(W, Wp);
    }
    dim3 gm((VV + NV - 1) / NV, BB);
    mesh_k<<<gm, 256, 0, stream>>>(x, xt, Gi, Wp, W, bias, out, use_xt, use_wp);
}

// Round 3
// 230.435 us; speedup vs baseline: 17.9611x; 17.9611x over previous
//
#include <hip/hip_runtime.h>
#include <hip/hip_bf16.h>
#include <cstdint>
#include <cstddef>

#define BB   4
#define CIN  64
#define VV   50000
#define COUT 128
#define NV   32            // vertices per block
#define KTOT 448           // CIN*7, kk = k*64 + c
#define KT   14            // KTOT/32 MFMA k-steps
#define PITCH 456          // G LDS row pitch in bf16 elems (448+8: stride%32dw==4)

typedef __attribute__((ext_vector_type(8))) short short8;
typedef __attribute__((ext_vector_type(4))) float f32x4;

// Static device buffers: no dependence on ws_size. Rewritten every launch
// (harness requires identical work per call; nothing here is call-count-gated).
__device__ float          g_xt[(size_t)BB * VV * CIN];   // x transposed [b][v][c], 51.2 MB
__device__ unsigned short g_wb[KT * 8 * 64 * 8];         // W in MFMA A-frag order, 114 KB

__device__ inline unsigned short f2bf(float f) {
    union { __hip_bfloat16 h; unsigned short u; } cv;
    cv.h = __float2bfloat16(f);
    return cv.u;
}

// ---------------------------------------------------------------------------
// Transpose x[B][C][V] -> g_xt[B][V][C]: per-vertex channel column becomes one
// contiguous 256B row, so the random-neighbor gather is coalesced.
// ---------------------------------------------------------------------------
__global__ __launch_bounds__(256) void transpose_k(const float* __restrict__ x) {
    __shared__ float tile[64][65];
    int b    = blockIdx.y;
    int v0   = blockIdx.x * 64;
    int lane = threadIdx.x & 63;
    int row  = threadIdx.x >> 6;  // 0..3
#pragma unroll
    for (int i = 0; i < 16; i++) {
        int c = row + 4 * i;
        int v = v0 + lane;
        float val = 0.f;
        if (v < VV) val = x[((size_t)b * CIN + c) * VV + v];
        tile[c][lane] = val;
    }
    __syncthreads();
#pragma unroll
    for (int i = 0; i < 16; i++) {
        int v = v0 + row + 4 * i;
        if (v < VV) g_xt[((size_t)b * VV + v) * CIN + lane] = tile[lane][row + 4 * i];
    }
}

// ---------------------------------------------------------------------------
// Pack W[o][c][k] (fp32) into bf16 MFMA A-fragments:
//   g_wb[(kt*8 + mt)*64 + lane][j]  =  W_bf16[m = mt*16 + (lane&15)]
//                                       [kk = kt*32 + (lane>>4)*8 + j]
// with kk = k*64 + c.  A k-step A-load is then one fully-coalesced dwordx4.
// ---------------------------------------------------------------------------
__global__ __launch_bounds__(256) void pack_wb_k(const float* __restrict__ W) {
    int idx = blockIdx.x * 256 + threadIdx.x;   // over KT*8*64 = 7168
    if (idx >= KT * 8 * 64) return;
    int lane = idx & 63;
    int mt   = (idx >> 6) & 7;
    int kt   = idx >> 9;
    int m    = mt * 16 + (lane & 15);
    int kb   = kt * 32 + (lane >> 4) * 8;
    union { unsigned short s[8]; short8 v; } u;
#pragma unroll
    for (int j = 0; j < 8; j++) {
        int kk = kb + j;
        int c  = kk & 63;
        int k  = kk >> 6;
        u.s[j] = f2bf(W[((size_t)m * CIN + c) * 7 + k]);
    }
    *(short8*)&g_wb[(size_t)idx * 8] = u.v;
}

__device__ inline void feats(float f0, float f1, float f2, float f3, float* g) {
    g[0] = f0;
    g[1] = f1 + f2 + f3;
    float p12 = f1 * f2, p13 = f1 * f3, p23 = f2 * f3;
    g[2] = p12 * f3;
    g[3] = p12 + p13 + p23;
    g[4] = f1 * f1 + f2 * f2 + f3 * f3;
    g[5] = fabsf(f1 - f2) + fabsf(f1 - f3) + fabsf(f2 - f3);
    g[6] = f1 * f1 * f1 + f2 * f2 * f2 + f3 * f3 * f3;
}

// ---------------------------------------------------------------------------
// Main kernel. Block = (batch b, 32-vertex tile).
//  Phase 1: gather f0..f3 (coalesced float2 via g_xt), 7 symmetric features,
//           packed bf16x2 ds_write_b32 into G[32][PITCH].
//  Phase 2: 4 waves x (2 m-tiles x 2 n-tiles) mfma_f32_16x16x32_bf16,
//           A from g_wb (global, coalesced), B via ds_read_b128.
// ---------------------------------------------------------------------------
__global__ __launch_bounds__(256) void mesh_k(
        const void* __restrict__ Gi, const float* __restrict__ bias,
        float* __restrict__ out) {
    __shared__ unsigned short Gl[NV * PITCH];   // 28.5 KB

    int b  = blockIdx.y;
    int v0 = blockIdx.x * NV;
    int t  = threadIdx.x;

    // Gi dtype sniff (int64 vs int32); wave-uniform.
    const unsigned* gu = (const unsigned*)Gi;
    bool is64 = ((gu[1] | gu[3] | gu[5] | gu[7]) == 0u);

    // ---- Phase 1 ----
    int lc2 = t & 31;   // channel pair {2*lc2, 2*lc2+1}
    int grp = t >> 5;   // 0..7
#pragma unroll
    for (int p = 0; p < 4; ++p) {
        int vv = p * 8 + grp;
        int v  = v0 + vv;
        unsigned* grow = (unsigned*)&Gl[vv * PITCH + lc2 * 2];  // feature k at dword k*32
        if (v < VV) {
            long long i0, i1, i2, i3;
            size_t gb = ((size_t)b * VV + v) * 4;
            if (is64) {
                const long long* g8 = (const long long*)Gi + gb;
                i0 = g8[0]; i1 = g8[1]; i2 = g8[2]; i3 = g8[3];
            } else {
                const int* g4 = (const int*)Gi + gb;
                i0 = g4[0]; i1 = g4[1]; i2 = g4[2]; i3 = g4[3];
            }
            int j0 = (int)(i0 < 0 ? 0 : (i0 >= VV ? VV - 1 : i0));
            int j1 = (int)(i1 < 0 ? 0 : (i1 >= VV ? VV - 1 : i1));
            int j2 = (int)(i2 < 0 ? 0 : (i2 >= VV ? VV - 1 : i2));
            int j3 = (int)(i3 < 0 ? 0 : (i3 >= VV ? VV - 1 : i3));

            const float* base = g_xt + (size_t)b * VV * CIN + lc2 * 2;
            float2 f0 = *(const float2*)(base + (size_t)j0 * CIN);
            float2 f1 = *(const float2*)(base + (size_t)j1 * CIN);
            float2 f2 = *(const float2*)(base + (size_t)j2 * CIN);
            float2 f3 = *(const float2*)(base + (size_t)j3 * CIN);

            float gx[7], gy[7];
            feats(f0.x, f1.x, f2.x, f3.x, gx);
            feats(f0.y, f1.y, f2.y, f3.y, gy);
#pragma unroll
            for (int k = 0; k < 7; k++)
                grow[k * 32] = (unsigned)f2bf(gx[k]) | ((unsigned)f2bf(gy[k]) << 16);
        } else {
#pragma unroll
            for (int k = 0; k < 7; k++) grow[k * 32] = 0u;
        }
    }
    __syncthreads();

    // ---- Phase 2: MFMA ----
    int w    = t >> 6;    // wave id: m rows 32w..32w+31
    int lane = t & 63;
    int l15  = lane & 15;
    int q    = lane >> 4;

    f32x4 acc[2][2] = {};

    const short8* wb = (const short8*)g_wb;
    for (int kt = 0; kt < KT; ++kt) {
        short8 a0 = wb[(kt * 8 + 2 * w    ) * 64 + lane];
        short8 a1 = wb[(kt * 8 + 2 * w + 1) * 64 + lane];
        short8 b0 = *(const short8*)&Gl[(l15     ) * PITCH + kt * 32 + q * 8];
        short8 b1 = *(const short8*)&Gl[(l15 + 16) * PITCH + kt * 32 + q * 8];
        acc[0][0] = __builtin_amdgcn_mfma_f32_16x16x32_bf16(a0, b0, acc[0][0], 0, 0, 0);
        acc[0][1] = __builtin_amdgcn_mfma_f32_16x16x32_bf16(a0, b1, acc[0][1], 0, 0, 0);
        acc[1][0] = __builtin_amdgcn_mfma_f32_16x16x32_bf16(a1, b0, acc[1][0], 0, 0, 0);
        acc[1][1] = __builtin_amdgcn_mfma_f32_16x16x32_bf16(a1, b1, acc[1][1], 0, 0, 0);
    }

    // ---- Epilogue: D col=lane&15 (v), row=(lane>>4)*4+reg (o) ----
#pragma unroll
    for (int mt = 0; mt < 2; ++mt) {
        int o = 32 * w + mt * 16 + q * 4;
        float bs[4];
#pragma unroll
        for (int r = 0; r < 4; ++r) bs[r] = bias[o + r];
#pragma unroll
        for (int nt = 0; nt < 2; ++nt) {
            int v = v0 + nt * 16 + l15;
            if (v < VV) {
                float* po = out + ((size_t)b * COUT + o) * VV + v;
#pragma unroll
                for (int r = 0; r < 4; ++r)
                    po[(size_t)r * VV] = acc[mt][nt][r] + bs[r];
            }
        }
    }
}

// ---------------------------------------------------------------------------
extern "C" void kernel_launch(void* const* d_in, const int* in_sizes, int n_in,
                              void* d_out, int out_size, void* d_ws, size_t ws_size,
                              hipStream_t stream) {
    const float* x    = (const float*)d_in[0];
    const void*  Gi   = d_in[1];
    const float* W    = (const float*)d_in[2];
    const float* bias = (const float*)d_in[3];
    float* out        = (float*)d_out;

    dim3 gt((VV + 63) / 64, BB);
    transpose_k<<<gt, 256, 0, stream>>>(x);
    pack_wb_k<<<(KT * 8 * 64 + 255) / 256, 256, 0, stream>>>(W);
    dim3 gm((VV + NV - 1) / NV, BB);
    mesh_k<<<gm, 256, 0, stream>>>(Gi, bias, out);
}

// Round 4
// 217.656 us; speedup vs baseline: 19.0157x; 1.0587x over previous
//
#include <hip/hip_runtime.h>
#include <hip/hip_bf16.h>
#include <cstdint>
#include <cstddef>

#define BB   4
#define CIN  64
#define VV   50000
#define COUT 128
#define NV   32            // vertices per block
#define KTOT 448           // CIN*7, kk = k*64 + c
#define KT   14            // KTOT/32 MFMA k-steps
#define PITCH 456          // G LDS row pitch in bf16 elems (448+8)

typedef __attribute__((ext_vector_type(8))) short short8;
typedef __attribute__((ext_vector_type(4))) float f32x4;

// Static device buffers (no ws_size dependence). Rewritten every launch.
__device__ float          g_xt[(size_t)BB * VV * CIN];   // x transposed [b][v][c], 51.2 MB
__device__ unsigned short g_wb[KT * 8 * 64 * 8];         // W in MFMA A-frag order, 114 KB

__device__ inline unsigned short f2bf(float f) {
    union { __hip_bfloat16 h; unsigned short u; } cv;
    cv.h = __float2bfloat16(f);
    return cv.u;
}

// ---------------------------------------------------------------------------
// Transpose x[B][C][V] -> g_xt[B][V][C], float4 both directions.
// Block: 64v x 64c tile. Read: thread (tc=t>>4, tv=t&15) loads float4 along v
// for c = tc+16i. Write: thread (tvv=t>>4, c4=t&15) stores float4 along c for
// v = tvv+16i. LDS tile[64][65]: both phases <=2-way bank aliasing (free).
// ---------------------------------------------------------------------------
__global__ __launch_bounds__(256) void transpose_k(const float* __restrict__ x) {
    __shared__ float tile[64][65];
    int b  = blockIdx.y;
    int v0 = blockIdx.x * 64;
    int t  = threadIdx.x;
    int tv = t & 15;    // v4-group: v = v0 + tv*4 .. +3
    int tc = t >> 4;    // c = tc + 16*i
#pragma unroll
    for (int i = 0; i < 4; i++) {
        int c = tc + 16 * i;
        int v = v0 + tv * 4;
        const float* src = x + ((size_t)b * CIN + c) * VV + v;
        float4 f;
        if (v + 3 < VV) {
            f = *(const float4*)src;
        } else {
            f.x = v + 0 < VV ? src[0] : 0.f;
            f.y = v + 1 < VV ? src[1] : 0.f;
            f.z = v + 2 < VV ? src[2] : 0.f;
            f.w = v + 3 < VV ? src[3] : 0.f;
        }
        tile[c][tv * 4 + 0] = f.x;
        tile[c][tv * 4 + 1] = f.y;
        tile[c][tv * 4 + 2] = f.z;
        tile[c][tv * 4 + 3] = f.w;
    }
    __syncthreads();
    int c4  = t & 15;   // c = c4*4 .. +3
    int tvv = t >> 4;   // v = v0 + tvv + 16*i
#pragma unroll
    for (int i = 0; i < 4; i++) {
        int v = v0 + tvv + 16 * i;
        if (v < VV) {
            float4 f;
            f.x = tile[c4 * 4 + 0][tvv + 16 * i];
            f.y = tile[c4 * 4 + 1][tvv + 16 * i];
            f.z = tile[c4 * 4 + 2][tvv + 16 * i];
            f.w = tile[c4 * 4 + 3][tvv + 16 * i];
            *(float4*)(g_xt + ((size_t)b * VV + v) * CIN + c4 * 4) = f;
        }
    }
}

// ---------------------------------------------------------------------------
// Pack W[o][c][k] (fp32) into bf16 MFMA A-fragments:
//   g_wb[(kt*8 + mt)*64 + lane][j] = W_bf16[m = mt*16 + (lane&15)]
//                                     [kk = kt*32 + (lane>>4)*8 + j], kk=k*64+c
// ---------------------------------------------------------------------------
__global__ __launch_bounds__(256) void pack_wb_k(const float* __restrict__ W) {
    int idx = blockIdx.x * 256 + threadIdx.x;   // over KT*8*64 = 7168
    if (idx >= KT * 8 * 64) return;
    int lane = idx & 63;
    int mt   = (idx >> 6) & 7;
    int kt   = idx >> 9;
    int m    = mt * 16 + (lane & 15);
    int kb   = kt * 32 + (lane >> 4) * 8;
    union { unsigned short s[8]; short8 v; } u;
#pragma unroll
    for (int j = 0; j < 8; j++) {
        int kk = kb + j;
        int c  = kk & 63;
        int k  = kk >> 6;
        u.s[j] = f2bf(W[((size_t)m * CIN + c) * 7 + k]);
    }
    *(short8*)&g_wb[(size_t)idx * 8] = u.v;
}

__device__ inline void feats(float f0, float f1, float f2, float f3, float* g) {
    g[0] = f0;
    g[1] = f1 + f2 + f3;
    float p12 = f1 * f2, p13 = f1 * f3, p23 = f2 * f3;
    g[2] = p12 * f3;
    g[3] = p12 + p13 + p23;
    g[4] = f1 * f1 + f2 * f2 + f3 * f3;
    g[5] = fabsf(f1 - f2) + fabsf(f1 - f3) + fabsf(f2 - f3);
    g[6] = f1 * f1 * f1 + f2 * f2 * f2 + f3 * f3 * f3;
}

// ---------------------------------------------------------------------------
// Main kernel. Block = (batch b, 32-vertex tile).
//  Phase 0: stage 32x4 neighbor indices into LDS (one global load each).
//  Phase 1: batched gather (16 independent float2 loads per thread in flight),
//           7 symmetric features, packed bf16x2 ds_write_b32 into G[32][PITCH].
//  Phase 2: 4 waves x (2m x 2n) mfma_f32_16x16x32_bf16; A from g_wb (global,
//           coalesced, L2-resident), B via ds_read_b128.
// ---------------------------------------------------------------------------
__global__ __launch_bounds__(256) void mesh_k(
        const void* __restrict__ Gi, const float* __restrict__ bias,
        float* __restrict__ out) {
    __shared__ unsigned short Gl[NV * PITCH];   // 28.5 KB
    __shared__ int Sidx[NV][4];                 // 512 B

    int b  = blockIdx.y;
    int v0 = blockIdx.x * NV;
    int t  = threadIdx.x;

    // Gi dtype sniff (int64 vs int32); wave-uniform.
    const unsigned* gu = (const unsigned*)Gi;
    bool is64 = ((gu[1] | gu[3] | gu[5] | gu[7]) == 0u);

    // ---- Phase 0: stage indices ----
    if (t < NV * 4) {
        int vv = t >> 2, j = t & 3;
        int v  = v0 + vv;
        long long val = 0;
        if (v < VV) {
            size_t gb = ((size_t)b * VV + v) * 4 + j;
            val = is64 ? ((const long long*)Gi)[gb] : (long long)((const int*)Gi)[gb];
        }
        Sidx[vv][j] = (int)(val < 0 ? 0 : (val >= VV ? VV - 1 : val));
    }
    __syncthreads();

    // ---- Phase 1: batched gather + features ----
    int lc2 = t & 31;   // channel pair {2*lc2, 2*lc2+1}
    int grp = t >> 5;   // 0..7
    int J[4][4];
#pragma unroll
    for (int p = 0; p < 4; ++p) {
        int vv = p * 8 + grp;
#pragma unroll
        for (int j = 0; j < 4; ++j) J[p][j] = Sidx[vv][j];
    }
    const float* base = g_xt + (size_t)b * VV * CIN + lc2 * 2;
    float2 F[4][4];
#pragma unroll
    for (int p = 0; p < 4; ++p)
#pragma unroll
        for (int j = 0; j < 4; ++j)
            F[p][j] = *(const float2*)(base + (size_t)J[p][j] * CIN);

#pragma unroll
    for (int p = 0; p < 4; ++p) {
        int vv = p * 8 + grp;
        unsigned* grow = (unsigned*)&Gl[vv * PITCH + lc2 * 2];  // feature k at dword k*32
        float gx[7], gy[7];
        feats(F[p][0].x, F[p][1].x, F[p][2].x, F[p][3].x, gx);
        feats(F[p][0].y, F[p][1].y, F[p][2].y, F[p][3].y, gy);
#pragma unroll
        for (int k = 0; k < 7; k++)
            grow[k * 32] = (unsigned)f2bf(gx[k]) | ((unsigned)f2bf(gy[k]) << 16);
        // v >= VV tail: garbage column, never stored (GEMM columns independent)
    }
    __syncthreads();

    // ---- Phase 2: MFMA ----
    int w    = t >> 6;    // wave id: m rows 32w..32w+31
    int lane = t & 63;
    int l15  = lane & 15;
    int q    = lane >> 4;

    f32x4 acc[2][2] = {};

    const short8* wb = (const short8*)g_wb;
#pragma unroll 2
    for (int kt = 0; kt < KT; ++kt) {
        short8 a0 = wb[(kt * 8 + 2 * w    ) * 64 + lane];
        short8 a1 = wb[(kt * 8 + 2 * w + 1) * 64 + lane];
        short8 b0 = *(const short8*)&Gl[(l15     ) * PITCH + kt * 32 + q * 8];
        short8 b1 = *(const short8*)&Gl[(l15 + 16) * PITCH + kt * 32 + q * 8];
        acc[0][0] = __builtin_amdgcn_mfma_f32_16x16x32_bf16(a0, b0, acc[0][0], 0, 0, 0);
        acc[0][1] = __builtin_amdgcn_mfma_f32_16x16x32_bf16(a0, b1, acc[0][1], 0, 0, 0);
        acc[1][0] = __builtin_amdgcn_mfma_f32_16x16x32_bf16(a1, b0, acc[1][0], 0, 0, 0);
        acc[1][1] = __builtin_amdgcn_mfma_f32_16x16x32_bf16(a1, b1, acc[1][1], 0, 0, 0);
    }

    // ---- Epilogue: D col=lane&15 (v), row=(lane>>4)*4+reg (o) ----
#pragma unroll
    for (int mt = 0; mt < 2; ++mt) {
        int o = 32 * w + mt * 16 + q * 4;
        float bs[4];
#pragma unroll
        for (int r = 0; r < 4; ++r) bs[r] = bias[o + r];
#pragma unroll
        for (int nt = 0; nt < 2; ++nt) {
            int v = v0 + nt * 16 + l15;
            if (v < VV) {
                float* po = out + ((size_t)b * COUT + o) * VV + v;
#pragma unroll
                for (int r = 0; r < 4; ++r)
                    po[(size_t)r * VV] = acc[mt][nt][r] + bs[r];
            }
        }
    }
}

// ---------------------------------------------------------------------------
extern "C" void kernel_launch(void* const* d_in, const int* in_sizes, int n_in,
                              void* d_out, int out_size, void* d_ws, size_t ws_size,
                              hipStream_t stream) {
    const float* x    = (const float*)d_in[0];
    const void*  Gi   = d_in[1];
    const float* W    = (const float*)d_in[2];
    const float* bias = (const float*)d_in[3];
    float* out        = (float*)d_out;

    dim3 gt((VV + 63) / 64, BB);
    transpose_k<<<gt, 256, 0, stream>>>(x);
    pack_wb_k<<<(KT * 8 * 64 + 255) / 256, 256, 0, stream>>>(W);
    dim3 gm((VV + NV - 1) / NV, BB);
    mesh_k<<<gm, 256, 0, stream>>>(Gi, bias, out);
}